// Round 2
// baseline (117.729 us; speedup 1.0000x reference)
//
#include <hip/hip_runtime.h>

// CrossAttention collapses algebraically:
//   age is broadcast across the pixel dim BEFORE the K/V projections, so
//   k[b,m,:] and v[b,m,:] are constant over m => every score row is constant
//   => softmax is exactly uniform => attended[b,n,:] = v_vec[b,:]
//   => out[b,n,d] = pixel[b,n,d] + age[b,:]·Wv[:,d] + bv[d]
// Q/Wq/bq/Wk/bk do not affect the output.

#define PIXEL_DIM 768
#define AGE_DIM   128
#define BB        8
#define NN        2048

#define ROW4      (PIXEL_DIM / 4)   // 192 float4 per row
#define BLOCKS_X  256               // blocks per batch
#define ROWS_PER_BLOCK (NN / BLOCKS_X)  // 8

// Kernel 1: v_vec[b,d] = sum_a age[b,a] * Wv[a,d] + bv[d]   (8 x 768 outputs)
__global__ void ca_compute_vvec(const float* __restrict__ age,
                                const float* __restrict__ Wv,
                                const float* __restrict__ bv,
                                float* __restrict__ v_vec) {
    int tid = blockIdx.x * blockDim.x + threadIdx.x;  // 0 .. 8*768-1
    if (tid >= BB * PIXEL_DIM) return;
    int b = tid / PIXEL_DIM;                          // 32-bit, cheap magic-mul
    int d = tid - b * PIXEL_DIM;
    const float* ab = age + b * AGE_DIM;
    float sum = bv[d];
    #pragma unroll 8
    for (int a = 0; a < AGE_DIM; ++a) {
        sum = fmaf(ab[a], Wv[a * PIXEL_DIM + d], sum);  // coalesced over d
    }
    v_vec[tid] = sum;
}

// Kernel 2: out[b,n,:] = pixel[b,n,:] + v_vec[b,:]
// block = 192 threads = one row of float4s; thread t owns column d=4t forever.
// grid = (BLOCKS_X, BB); each block does ROWS_PER_BLOCK rows.
// No division/mod anywhere; v_vec float4 loaded once per thread.
__global__ void __launch_bounds__(ROW4)
ca_add_bcast(const float4* __restrict__ pixel,
             const float4* __restrict__ v_vec,
             float4* __restrict__ out) {
    const int t = threadIdx.x;          // 0..191  -> d = 4t
    const int b = blockIdx.y;           // 0..7
    const int n0 = blockIdx.x * ROWS_PER_BLOCK;

    const float4 v = v_vec[b * ROW4 + t];   // L2-resident, loaded once

    long base = ((long)b * NN + n0) * ROW4 + t;
    #pragma unroll
    for (int r = 0; r < ROWS_PER_BLOCK; ++r) {
        float4 p = pixel[base];
        float4 o;
        o.x = p.x + v.x;
        o.y = p.y + v.y;
        o.z = p.z + v.z;
        o.w = p.w + v.w;
        out[base] = o;
        base += ROW4;                   // next row, same column
    }
}

extern "C" void kernel_launch(void* const* d_in, const int* in_sizes, int n_in,
                              void* d_out, int out_size, void* d_ws, size_t ws_size,
                              hipStream_t stream) {
    const float* pixel = (const float*)d_in[0];  // [8, 2048, 768]
    const float* age   = (const float*)d_in[1];  // [8, 128]
    // d_in[2..5] = Wq, bq, Wk, bk  -- unused (see header comment)
    const float* Wv    = (const float*)d_in[6];  // [128, 768]
    const float* bv    = (const float*)d_in[7];  // [768]
    float* out   = (float*)d_out;
    float* v_vec = (float*)d_ws;                 // 8*768 floats = 24 KB

    {
        int threads = 256;
        int total = BB * PIXEL_DIM;              // 6144
        int blocks = (total + threads - 1) / threads;
        ca_compute_vvec<<<blocks, threads, 0, stream>>>(age, Wv, bv, v_vec);
    }
    {
        dim3 grid(BLOCKS_X, BB);                 // 256 x 8 = 2048 blocks
        ca_add_bcast<<<grid, ROW4, 0, stream>>>((const float4*)pixel,
                                                (const float4*)v_vec,
                                                (float4*)out);
    }
}